// Round 3
// baseline (107.895 us; speedup 1.0000x reference)
//
#include <hip/hip_runtime.h>
#include <hip/hip_bf16.h>
#include <cfloat>

// DGG_StraightThrough: softmax over a singleton axis makes log_p == 0 exactly,
// so y == temp broadcast over batch. Output evaluates elementwise to:
//   non-topk: (0 - t) + t == +0.0 exactly
//   topk:     (1 - t) + t   (identical fp32 expression as reference)
// topk = top-8 per row of temp, ties -> lowest index (matches jax.lax.top_k).
//
// Kernel 1 (2048 blocks x 256 thr, full 32 waves/CU occupancy):
//   per-row top-8 (register scan + shfl butterflies, one barrier) -> d_ws,
//   then zero-fill the row for all 4 batches (stores never drained in-kernel).
// Kernel 2 (tiny): patch 8x4 entries per row from d_ws.

#define NROW 2048
#define KTOP 8
#define NB 4

__global__ __launch_bounds__(256) void dgg_topk_fill(
    const float* __restrict__ temp, float* __restrict__ out,
    float* __restrict__ wsV, int* __restrict__ wsI)
{
    const int n = blockIdx.x;          // row
    const int t = threadIdx.x;
    const int w = t >> 6;              // wave 0..3
    const int l = t & 63;              // lane

    __shared__ float cv[32];
    __shared__ int   ci[32];

    // ---- load: wave w owns elements [w*512, (w+1)*512), coalesced float4 ----
    const float4* row4 = (const float4*)(temp + (size_t)n * NROW);
    const float4 f0 = row4[(w << 7) + l];        // elems w*512 + 4l + c
    const float4 f1 = row4[(w << 7) + 64 + l];   // elems w*512 + 256 + 4l + c

    const int base = (w << 9) + (l << 2);
    float fv[8] = { f0.x, f0.y, f0.z, f0.w, f1.x, f1.y, f1.z, f1.w };
    int   gi[8] = { base, base + 1, base + 2, base + 3,
                    base + 256, base + 257, base + 258, base + 259 };

    // ---- per-wave top-8: 8 passes, all static register indexing ----
    float sv[KTOP]; int si[KTOP];
    #pragma unroll
    for (int p = 0; p < KTOP; ++p) {
        float bv = -FLT_MAX; int bi = 0x7fffffff;
        #pragma unroll
        for (int i = 0; i < 8; ++i) {
            // within-lane indices scanned in increasing order: strict > keeps lowest idx
            if (fv[i] > bv) { bv = fv[i]; bi = gi[i]; }
        }
        #pragma unroll
        for (int m = 1; m < 64; m <<= 1) {
            float ov = __shfl_xor(bv, m);
            int   oi = __shfl_xor(bi, m);
            if (ov > bv || (ov == bv && oi < bi)) { bv = ov; bi = oi; }
        }
        sv[p] = bv; si[p] = bi;
        #pragma unroll
        for (int i = 0; i < 8; ++i) if (gi[i] == bi) fv[i] = -FLT_MAX;
    }

    // ---- publish wave candidates (unrolled -> static reg indexing) ----
    #pragma unroll
    for (int p = 0; p < KTOP; ++p)
        if (l == p) { cv[(w << 3) + p] = sv[p]; ci[(w << 3) + p] = si[p]; }
    __syncthreads();

    // ---- wave 0 merges 32 candidates; waves 1-3 fall through to the fill ----
    if (w == 0) {
        float mv = (l < 32) ? cv[l] : -FLT_MAX;
        int   mi = (l < 32) ? ci[l] : 0x7fffffff;
        #pragma unroll
        for (int p = 0; p < KTOP; ++p) {
            float bv = mv; int bi = mi;
            #pragma unroll
            for (int m = 1; m < 64; m <<= 1) {
                float ov = __shfl_xor(bv, m);
                int   oi = __shfl_xor(bi, m);
                if (ov > bv || (ov == bv && oi < bi)) { bv = ov; bi = oi; }
            }
            if (l == 0) { wsV[(n << 3) + p] = bv; wsI[(n << 3) + p] = bi; }
            if (mi == bi) mv = -FLT_MAX;   // candidate indices are unique
        }
    }

    // ---- zero-fill this row for all 4 batches (no drain; kernel end handles) ----
    const float4 z = make_float4(0.f, 0.f, 0.f, 0.f);
    #pragma unroll
    for (int b = 0; b < NB; ++b) {
        float4* o4 = (float4*)(out + ((size_t)b * NROW + n) * NROW);
        o4[t]       = z;
        o4[t + 256] = z;
    }
}

__global__ __launch_bounds__(256) void dgg_patch(
    const float* __restrict__ wsV, const int* __restrict__ wsI,
    float* __restrict__ out)
{
    const int r = blockIdx.x * 256 + threadIdx.x;   // row
    #pragma unroll
    for (int p = 0; p < KTOP; ++p) {
        const float tv  = wsV[(r << 3) + p];
        const int   idx = wsI[(r << 3) + p];
        const float val = (1.0f - tv) + tv;         // same fp32 expr as reference
        #pragma unroll
        for (int b = 0; b < NB; ++b)
            out[((size_t)b * NROW + r) * NROW + idx] = val;
    }
}

extern "C" void kernel_launch(void* const* d_in, const int* in_sizes, int n_in,
                              void* d_out, int out_size, void* d_ws, size_t ws_size,
                              hipStream_t stream) {
    // inputs: 0:x  1:temp  2:W_proj  3:b_proj  4:W_dist  5:b_dist
    const float* temp = (const float*)d_in[1];
    float* out = (float*)d_out;
    float* wsV = (float*)d_ws;
    int*   wsI = (int*)((char*)d_ws + (size_t)NROW * KTOP * sizeof(float));

    dgg_topk_fill<<<NROW, 256, 0, stream>>>(temp, out, wsV, wsI);
    dgg_patch<<<NROW / 256, 256, 0, stream>>>(wsV, wsI, out);
}